// Round 1
// 82.009 us; speedup vs baseline: 1.0032x; 1.0032x over previous
//
#include <hip/hip_runtime.h>
#include <cstdint>

// Fully-fused quantum circuit simulator, v2: 3-LDS-phase-per-layer schedule.
//
// Chunk layout (1024 amps in LDS, sw-swizzled): bit 0..7 = d0..d7 (data),
// bit 8 = a0, bit 9 = a1 (current layer's ancillas). Refinement tree as
// before: wave (b,s1,s2) recomputes L0 and L1(s1) redundantly.
//
// Key change vs v1: H on FRESH ancillas (|00> -> uniform/2) is folded into
// the extract as a broadcast (all 4 anc lane-groups read the same parent
// slice; the 1/2 is folded into sUpre[L][4]). This removes the two "head"
// phases where 75% of lanes held zeros. Per layer only 3 regroup phases:
//   A {d4..7}: Upre(d4..7), CRZ j=4..7, M4(4,5), M4(6,7), off(5,6)
//   B {d0..3}: Upre(d0..3), CRZ j=0..3, M4(0,1), M4(2,3),
//              [L==1: H(anc) via shfl_xor], CCRX(a0;d0,d1), CCRX(a1;d2,d3)
//              (anc controls are lane-predicates), off(1,2)
//   C {d2..5}: off(3,4), [L==2: Upost(d2..d5)]
// Final phase {d0,d1,d6,d7}: Upost(d0,d1,d6,d7) + measurement.
// All CRZ cos/sin are precomputed once in setup (sCS), no per-phase sincos.
// Commutation checks: every reordered pair acts on disjoint wires.

struct F2 { float x, y; };

__device__ __forceinline__ F2 cmul(F2 a, F2 b) {
  return F2{ a.x * b.x - a.y * b.y, a.x * b.y + a.y * b.x };
}
__device__ __forceinline__ F2 cfma2(F2 a, F2 b, F2 c) { // a*b + c
  return F2{ fmaf(a.x, b.x, fmaf(-a.y, b.y, c.x)),
             fmaf(a.x, b.y, fmaf( a.y, b.x, c.y)) };
}

// deposit bits of x into the set positions of compile-time MASK (low->high)
template<uint32_t MASK>
__device__ __forceinline__ uint32_t pdep10(uint32_t x) {
  uint32_t r = 0;
  #pragma unroll
  for (int b = 0; b < 10; ++b) {
    if (MASK & (1u << b)) { r |= (x & 1u) << b; x >>= 1; }
  }
  return r;
}

// LDS anti-bank-conflict swizzle (bits 5..9 XOR into 0..4)
__device__ __forceinline__ uint32_t sw(uint32_t i) { return i ^ ((i >> 5) & 31u); }

template<uint32_t MASK>
__device__ __forceinline__ void readGrp(const F2* lds, int lane, F2 a[16]) {
  const uint32_t base = pdep10<(~MASK) & 0x3FFu>((uint32_t)lane);
  #pragma unroll
  for (uint32_t j = 0; j < 16; ++j) a[j] = lds[sw(base | pdep10<MASK>(j))];
}
template<uint32_t MASK>
__device__ __forceinline__ void writeGrp(F2* lds, int lane, const F2 a[16]) {
  const uint32_t base = pdep10<(~MASK) & 0x3FFu>((uint32_t)lane);
  #pragma unroll
  for (uint32_t j = 0; j < 16; ++j) lds[sw(base | pdep10<MASK>(j))] = a[j];
}

// single-qubit 2x2 on local (reg) bit p
__device__ __forceinline__ void gate1(F2 a[16], const F2 U[4], int p) {
  const int s = 1 << p;
  #pragma unroll
  for (int i = 0; i < 16; ++i) {
    if (i & s) continue;
    F2 a0 = a[i], a1 = a[i | s];
    a[i]     = cfma2(U[0], a0, cmul(U[1], a1));
    a[i | s] = cfma2(U[2], a0, cmul(U[3], a1));
  }
}

// fused RZZ*RYY*RXX: m = {alpha,beta,gamma,delta}; p = lower qubit's reg bit
__device__ __forceinline__ void gateM4(F2 a[16], const F2 m[4], int p, int q) {
  const int sp = 1 << p, sq = 1 << q;
  #pragma unroll
  for (int i = 0; i < 16; ++i) {
    if (i & (sp | sq)) continue;
    F2 v0 = a[i], v1 = a[i | sq], v2 = a[i | sp], v3 = a[i | sp | sq];
    a[i]           = cfma2(m[0], v0, cmul(m[2], v3));
    a[i | sp | sq] = cfma2(m[2], v0, cmul(m[0], v3));
    a[i | sq]      = cfma2(m[1], v1, cmul(m[3], v2));
    a[i | sp]      = cfma2(m[3], v1, cmul(m[1], v2));
  }
}

// CRZ diagonal for the 4 data qubits mapped to reg bits 0..3.
// CS0/CS1 point at {cos(pw/2), sin(pw/2)} for anc0/anc1 channels, entries
// [t] = data qubit (base+t). Factor for d_j=1: e^{-i pw/2} if anc=0,
// e^{+i pw/2} if anc=1 (matches jnp diag(1,1,e,conj(e)) with wires (j,a)).
// anc bits are lane bits 4 (a0) and 5 (a1) in ALL groupings used here.
__device__ __forceinline__ void crz4(F2 a[16], const F2* CS0, const F2* CS1,
                                     int lane) {
  const float g0 = (lane & 16) ? 1.f : -1.f;
  const float g1 = (lane & 32) ? 1.f : -1.f;
  #pragma unroll
  for (int t = 0; t < 4; ++t) {
    const F2 c0 = CS0[t], c1 = CS1[t];
    const F2 g = cmul(F2{c0.x, g0 * c0.y}, F2{c1.x, g1 * c1.y});
    #pragma unroll
    for (int j = 0; j < 16; ++j)
      if (j & (1 << t)) a[j] = cmul(a[j], g);
  }
}

// H on an anc LANE bit (16 -> a0, 32 -> a1) via shfl_xor:
// v0' = (v0+v1)R ; v1' = (v0-v1)R
__device__ __forceinline__ void hAnc(F2 a[16], int bit, int lane) {
  const float R = 0.70710678118654752f;
  const float s = (lane & bit) ? -1.f : 1.f;
  #pragma unroll
  for (int j = 0; j < 16; ++j) {
    const float px = __shfl_xor(a[j].x, bit, 64);
    const float py = __shfl_xor(a[j].y, bit, 64);
    a[j].x = fmaf(s, a[j].x, px) * R;
    a[j].y = fmaf(s, a[j].y, py) * R;
  }
}

// Both CCRX gates in grouping B {d0..3}: controls are anc LANE bits
// (predicates) + one reg bit; target a reg bit. RX(pi/4).
__device__ __forceinline__ void ccrx2(F2 a[16], int lane) {
  const float C = 0.92387953251128674f;  // cos(pi/8)
  const float S = 0.38268343236508978f;  // sin(pi/8)
  if (lane & 16) {                       // a0 set: ctrl d0 (bit0), tgt d1 (bit1)
    #pragma unroll
    for (int i = 0; i < 16; ++i) {
      if ((i & 3) != 1) continue;        // bit0=1, bit1=0
      F2 a0 = a[i], a1 = a[i | 2];
      a[i]     = F2{ fmaf(C, a0.x,  S * a1.y), fmaf(C, a0.y, -S * a1.x) };
      a[i | 2] = F2{ fmaf(C, a1.x,  S * a0.y), fmaf(C, a1.y, -S * a0.x) };
    }
  }
  if (lane & 32) {                       // a1 set: ctrl d2 (bit2), tgt d3 (bit3)
    #pragma unroll
    for (int i = 0; i < 16; ++i) {
      if ((i & 12) != 4) continue;       // bit2=1, bit3=0
      F2 a0 = a[i], a1 = a[i | 8];
      a[i]     = F2{ fmaf(C, a0.x,  S * a1.y), fmaf(C, a0.y, -S * a1.x) };
      a[i | 8] = F2{ fmaf(C, a1.x,  S * a0.y), fmaf(C, a1.y, -S * a0.x) };
    }
  }
}

__device__ __forceinline__ void rot_rx(F2 m[4], float t) {
  float c, s; __sincosf(0.5f * t, &s, &c);
  m[0] = F2{c, 0.f}; m[1] = F2{0.f, -s}; m[2] = F2{0.f, -s}; m[3] = F2{c, 0.f};
}
__device__ __forceinline__ void rot_ry(F2 m[4], float t) {
  float c, s; __sincosf(0.5f * t, &s, &c);
  m[0] = F2{c, 0.f}; m[1] = F2{-s, 0.f}; m[2] = F2{s, 0.f}; m[3] = F2{c, 0.f};
}
__device__ __forceinline__ void rot_rz(F2 m[4], float t) {
  float c, s; __sincosf(0.5f * t, &s, &c);
  m[0] = F2{c, -s}; m[1] = F2{0.f, 0.f}; m[2] = F2{0.f, 0.f}; m[3] = F2{c, s};
}
__device__ __forceinline__ void mat2mul(F2 o[4], const F2 A[4], const F2 B[4]) {
  o[0] = cfma2(A[0], B[0], cmul(A[1], B[2]));
  o[1] = cfma2(A[0], B[1], cmul(A[1], B[3]));
  o[2] = cfma2(A[2], B[0], cmul(A[3], B[2]));
  o[3] = cfma2(A[2], B[1], cmul(A[3], B[3]));
}

// One full layer, 3 LDS phases. On entry for L==0, a[] already holds the
// product state in grouping A {d4..7}; for L>0 the extract (with anc-H
// broadcast) happens here. On exit amp[] holds the full 1024-amp chunk.
template<int L>
__device__ __forceinline__ void do_layer(F2 a[16], F2* amp, int lane, int sel,
    const F2 (*Upre)[4], const F2 (*M4)[4], const F2* CS0, const F2* CS1,
    const F2 (*Upost)[4])
{
  // ---- Phase A: grouping 0x0F0 (regs d4..7; lanes d0..3, a0, a1) ----
  if constexpr (L > 0) {
    // extract slice sel of parent; all 4 anc lane-groups read the SAME
    // address (LDS broadcast) -> H@fresh-anc folded (1/2 is in Upre[4]).
    #pragma unroll
    for (int j = 0; j < 16; ++j)
      a[j] = amp[sw((uint32_t)((lane & 15) | (j << 4) | (sel << 8)))];
    __syncthreads();  // slice fully read before amp is overwritten
    gate1(a, Upre[4], 0); gate1(a, Upre[5], 1);
    gate1(a, Upre[6], 2); gate1(a, Upre[7], 3);
  }
  crz4(a, CS0 + 4, CS1 + 4, lane);  // CRZ factors j=4..7
  gateM4(a, M4[2], 0, 1);           // pair (4,5)
  gateM4(a, M4[3], 2, 3);           // pair (6,7)
  gateM4(a, M4[6], 1, 2);           // off  (5,6)
  writeGrp<0x0F0u>(amp, lane, a);
  __syncthreads();

  // ---- Phase B: grouping 0x00F (regs d0..3; lanes d4..7, a0, a1) ----
  readGrp<0x00Fu>(amp, lane, a);
  if constexpr (L > 0) {            // L0's Upre is already in the build
    gate1(a, Upre[0], 0); gate1(a, Upre[1], 1);
    gate1(a, Upre[2], 2); gate1(a, Upre[3], 3);
  }
  crz4(a, CS0, CS1, lane);          // CRZ factors j=0..3
  gateM4(a, M4[0], 0, 1);           // pair (0,1)
  gateM4(a, M4[1], 2, 3);           // pair (2,3)
  if constexpr (L == 1) { hAnc(a, 16, lane); hAnc(a, 32, lane); }
  ccrx2(a, lane);                   // CCRX(a0;d0,d1), CCRX(a1;d2,d3)
  gateM4(a, M4[4], 1, 2);           // off  (1,2)
  writeGrp<0x00Fu>(amp, lane, a);
  __syncthreads();

  // ---- Phase C: grouping 0x03C (regs d2..5; lanes d0,d1,d6,d7,a0,a1) ----
  readGrp<0x03Cu>(amp, lane, a);
  gateM4(a, M4[5], 1, 2);           // off  (3,4)
  if constexpr (L == 2) {
    gate1(a, Upost[2], 0); gate1(a, Upost[3], 1);
    gate1(a, Upost[4], 2); gate1(a, Upost[5], 3);
  }
  writeGrp<0x03Cu>(amp, lane, a);
  __syncthreads();
}

__global__ __launch_bounds__(128) void zero_out_k(float* out) {
  out[threadIdx.x] = 0.f;
}

__global__ __launch_bounds__(64)
void qpie_fused(const float* __restrict__ x, const float* __restrict__ w,
                const float* __restrict__ pwg, float* __restrict__ out)
{
  __shared__ F2 amp[1024];
  __shared__ F2 sUpre[3][8][4];
  __shared__ F2 sUpost[8][4];
  __shared__ F2 sM4[3][7][4];
  __shared__ F2 sCS[3][2][8];   // {cos(pw/2), sin(pw/2)} per (L, anc, qubit)

  const int lane = threadIdx.x;
  const int blk  = blockIdx.x;          // b*16 + s1*4 + s2
  const int b  = blk >> 4;
  const int s1 = (blk >> 2) & 3;
  const int s2 = blk & 3;

  // ---- all gate parameters for all 3 layers (single wave, lane-parallel)
  if (lane < 24) {
    const int Lp = lane >> 3, q = lane & 7;
    F2 tail[4];
    if (Lp == 0) {
      const float R = 0.70710678118654752f;
      tail[0] = F2{R, 0.f}; tail[1] = F2{R, 0.f};
      tail[2] = F2{R, 0.f}; tail[3] = F2{-R, 0.f};
    } else {
      F2 rx[4], ry[4], rz[4], t0[4];
      rot_rx(rx, w[(Lp - 1) * 48 + 24 + 3 * q]);
      rot_ry(ry, w[(Lp - 1) * 48 + 24 + 3 * q + 1]);
      rot_rz(rz, w[(Lp - 1) * 48 + 24 + 3 * q + 2]);
      mat2mul(t0, ry, rx);
      mat2mul(tail, rz, t0);
    }
    F2 rot[4];
    if ((Lp & 1) == 0) rot_ry(rot, x[b * 8 + q]); else rot_rx(rot, x[b * 8 + q]);
    F2 u[4]; mat2mul(u, rot, tail);
    if (q == 4) {   // fold the fresh-anc H⊗H factor (1/2) into qubit-4's gate
      #pragma unroll
      for (int k = 0; k < 4; ++k) { u[k].x *= 0.5f; u[k].y *= 0.5f; }
    }
    #pragma unroll
    for (int k = 0; k < 4; ++k) sUpre[Lp][q][k] = u[k];
  } else if (lane < 45) {
    const int t = lane - 24;
    const int Lp = t / 7, p = t % 7;
    float cx, sx, cy, sy, cz, sz;
    __sincosf(0.5f * w[Lp * 48 + 3 * p    ], &sx, &cx);
    __sincosf(0.5f * w[Lp * 48 + 3 * p + 1], &sy, &cy);
    __sincosf(0.5f * w[Lp * 48 + 3 * p + 2], &sz, &cz);
    const F2 e  = F2{cz, -sz};
    const F2 eb = F2{cz,  sz};
    const float P = cx * cy + sx * sy, Q = cx * cy - sx * sy;
    sM4[Lp][p][0] = F2{ e.x * P,  e.y * P };
    sM4[Lp][p][1] = F2{ eb.x * Q, eb.y * Q };
    sM4[Lp][p][2] = cmul(e,  F2{0.f,  sy * cx - sx * cy});
    sM4[Lp][p][3] = cmul(eb, F2{0.f, -(sx * cy + sy * cx)});
  } else if (lane < 53) {
    const int q = lane - 45;
    F2 rx[4], ry[4], rz[4], t0[4], t1[4];
    rot_rx(rx, w[2 * 48 + 24 + 3 * q]);
    rot_ry(ry, w[2 * 48 + 24 + 3 * q + 1]);
    rot_rz(rz, w[2 * 48 + 24 + 3 * q + 2]);
    mat2mul(t0, ry, rx); mat2mul(t1, rz, t0);
    #pragma unroll
    for (int k = 0; k < 4; ++k) sUpost[q][k] = t1[k];
  }
  if (lane < 48) {   // CRZ cos/sin table, once for the whole kernel
    const float v = pwg[lane];
    float c, s; __sincosf(0.5f * v, &s, &c);
    (&sCS[0][0][0])[lane] = F2{c, s};
  }
  __syncthreads();

  F2 a[16];

  // ===== Layer 0: product state directly in grouping A {d4..7} =====
  // lane bits 0..3 = d0..3; regs = d4..7; anc lane-groups all identical
  // (H⊗H|00> broadcast; the 1/2 is folded into sUpre[0][4]).
  {
    F2 lf = (lane & 1) ? sUpre[0][0][2] : sUpre[0][0][0];
    #pragma unroll
    for (int t = 1; t < 4; ++t)
      lf = cmul(lf, ((lane >> t) & 1) ? sUpre[0][t][2] : sUpre[0][t][0]);
    F2 c45[4], c67[4];
    #pragma unroll
    for (int k = 0; k < 4; ++k) {
      c45[k] = cmul((k & 1) ? sUpre[0][4][2] : sUpre[0][4][0],
                    (k & 2) ? sUpre[0][5][2] : sUpre[0][5][0]);
      c67[k] = cmul((k & 1) ? sUpre[0][6][2] : sUpre[0][6][0],
                    (k & 2) ? sUpre[0][7][2] : sUpre[0][7][0]);
    }
    #pragma unroll
    for (int j = 0; j < 16; ++j)
      a[j] = cmul(lf, cmul(c45[j & 3], c67[j >> 2]));
  }
  do_layer<0>(a, amp, lane, 0,  sUpre[0], sM4[0], sCS[0][0], sCS[0][1], sUpost);
  do_layer<1>(a, amp, lane, s1, sUpre[1], sM4[1], sCS[1][0], sCS[1][1], sUpost);
  do_layer<2>(a, amp, lane, s2, sUpre[2], sM4[2], sCS[2][0], sCS[2][1], sUpost);

  // ===== Final phase: grouping 0x0C3 (regs d0,d1,d6,d7; lanes d2..d5,a0,a1)
  readGrp<0x0C3u>(amp, lane, a);
  gate1(a, sUpost[0], 0); gate1(a, sUpost[1], 1);
  gate1(a, sUpost[6], 2); gate1(a, sUpost[7], 3);
  float T = 0.f, E0 = 0.f, E1 = 0.f, E6 = 0.f, E7 = 0.f;
  #pragma unroll
  for (int j = 0; j < 16; ++j) {
    const float p = a[j].x * a[j].x + a[j].y * a[j].y;
    T += p;
    E0 += (j & 1) ? -p : p;
    E1 += (j & 2) ? -p : p;
    E6 += (j & 4) ? -p : p;
    E7 += (j & 8) ? -p : p;
  }
  float ev[8];
  ev[0] = E0; ev[1] = E1; ev[6] = E6; ev[7] = E7;
  ev[2] = (lane & 1) ? -T : T;   // d2..d5 are lane bits 0..3
  ev[3] = (lane & 2) ? -T : T;
  ev[4] = (lane & 4) ? -T : T;
  ev[5] = (lane & 8) ? -T : T;
  #pragma unroll
  for (int q = 0; q < 8; ++q) {
    float v = ev[q];
    #pragma unroll
    for (int k = 1; k < 64; k <<= 1) v += __shfl_xor(v, k, 64);
    if (lane == 0) atomicAdd(&out[b * 8 + q], v);
  }
}

extern "C" void kernel_launch(void* const* d_in, const int* in_sizes, int n_in,
                              void* d_out, int out_size, void* d_ws, size_t ws_size,
                              hipStream_t stream) {
  (void)in_sizes; (void)n_in; (void)out_size; (void)d_ws; (void)ws_size;
  const float* x   = (const float*)d_in[0];   // (16,8)
  const float* w   = (const float*)d_in[1];   // (3,48)
  const float* pwg = (const float*)d_in[2];   // (3,2,8)
  float* out = (float*)d_out;                 // (16,8)

  zero_out_k<<<1, 128, 0, stream>>>(out);
  qpie_fused<<<256, 64, 0, stream>>>(x, w, pwg, out);
}